// Round 7
// baseline (213.883 us; speedup 1.0000x reference)
//
#include <hip/hip_runtime.h>

#define SEQ 4096
#define DMODEL 1024
#define HEADS 16
#define HD 64
#define NQKV 3072

typedef __attribute__((ext_vector_type(8))) __bf16 bf16x8;
typedef __attribute__((ext_vector_type(8))) short short8;
typedef __attribute__((ext_vector_type(4))) float f32x4;
typedef __attribute__((ext_vector_type(16))) float f32x16;
typedef __attribute__((ext_vector_type(4))) unsigned int u32x4;

__device__ __forceinline__ unsigned short f2bf(float f) {
    unsigned u = __builtin_bit_cast(unsigned, f);
    return (unsigned short)((u + 0x7fffu + ((u >> 16) & 1u)) >> 16);
}
__device__ __forceinline__ float bf2f(unsigned short h) {
    return __builtin_bit_cast(float, (unsigned)h << 16);
}
__device__ __forceinline__ unsigned cvt_pk_bf16(float lo, float hi) {
    unsigned r;
    asm("v_cvt_pk_bf16_f32 %0, %1, %2" : "=v"(r) : "v"(lo), "v"(hi));
    return r;
}

__device__ __forceinline__ void gload16(const void* g, void* l) {
    __builtin_amdgcn_global_load_lds(
        (const __attribute__((address_space(1))) unsigned int*)g,
        (__attribute__((address_space(3))) unsigned int*)l, 16, 0, 0);
}

// ---------------- fp32 -> bf16 convert ----------------
__global__ void f2bf_vec(const float* __restrict__ in, unsigned short* __restrict__ out, int n4) {
    int i = blockIdx.x * 256 + threadIdx.x;
    int stride = gridDim.x * 256;
    for (; i < n4; i += stride) {
        float4 f = reinterpret_cast<const float4*>(in)[i];
        ushort4 o;
        o.x = f2bf(f.x); o.y = f2bf(f.y); o.z = f2bf(f.z); o.w = f2bf(f.w);
        reinterpret_cast<ushort4*>(out)[i] = o;
    }
}

// ---------------- bf16 GEMM, C = A(MxK) * B(NxK)^T ----------------
template <int EPI>
__global__ __launch_bounds__(256) void gemm_bt(const unsigned short* __restrict__ A,
                                               const unsigned short* __restrict__ B,
                                               float* __restrict__ outF,
                                               unsigned short* __restrict__ outB,
                                               int M, int N, int K) {
    alignas(16) __shared__ unsigned short a_lds[128 * 32];
    alignas(16) __shared__ unsigned short b_lds[128 * 32];
    const int tid = threadIdx.x;
    const int wave = tid >> 6, lane = tid & 63;
    const int l16 = lane & 15, g = lane >> 4;
    const int wr = wave >> 1, wc = wave & 1;
    const int bm = blockIdx.x, bn = blockIdx.y;

    const int lrow = lane >> 2;
    const int lcol = (lane & 3) * 8;

    const unsigned short* Ag = A + (size_t)(bm * 128 + lrow) * K + lcol;
    const unsigned short* Bg = B + (size_t)(bn * 128 + lrow) * K + lcol;

    f32x4 acc[4][4] = {};

    for (int k0 = 0; k0 < K; k0 += 32) {
#pragma unroll
        for (int j = 0; j < 2; ++j) {
            int chunk = wave * 2 + j;
            gload16(Ag + (size_t)(chunk * 16) * K + k0, a_lds + chunk * 512);
            gload16(Bg + (size_t)(chunk * 16) * K + k0, b_lds + chunk * 512);
        }
        __syncthreads();
        bf16x8 af[4], bfr[4];
#pragma unroll
        for (int m = 0; m < 4; ++m)
            af[m] = *reinterpret_cast<const bf16x8*>(a_lds + (wr * 64 + m * 16 + l16) * 32 + g * 8);
#pragma unroll
        for (int n = 0; n < 4; ++n)
            bfr[n] = *reinterpret_cast<const bf16x8*>(b_lds + (wc * 64 + n * 16 + l16) * 32 + g * 8);
#pragma unroll
        for (int m = 0; m < 4; ++m)
#pragma unroll
            for (int n = 0; n < 4; ++n)
                acc[m][n] = __builtin_amdgcn_mfma_f32_16x16x32_bf16(af[m], bfr[n], acc[m][n], 0, 0, 0);
        __syncthreads();
    }

#pragma unroll
    for (int m = 0; m < 4; ++m)
#pragma unroll
        for (int n = 0; n < 4; ++n)
#pragma unroll
            for (int r = 0; r < 4; ++r) {
                int row = bm * 128 + wr * 64 + m * 16 + g * 4 + r;
                int col = bn * 128 + wc * 64 + n * 16 + l16;
                float v = acc[m][n][r];
                if (EPI == 0) {
                    int part = col >> 10;
                    int hd = col & 1023;
                    int h = hd >> 6, d = hd & 63;
                    outB[(size_t)((part * HEADS + h) * SEQ + row) * HD + d] = f2bf(v);
                } else {
                    outF[(size_t)row * N + col] = v;
                }
            }
}

// ---------------- RoPE in place on Q,K (Q scaled by 1/8 * log2e) ----------------
__global__ __launch_bounds__(256) void rope_kernel(unsigned short* qkv, const int* __restrict__ pos) {
    int idx = blockIdx.x * 256 + threadIdx.x;
    int chunk = idx & 7;
    int row = idx >> 3;
    int s = row & (SEQ - 1);
    int ph = row >> 12;
    float p = (float)pos[s];
    float scale = (ph < HEADS) ? 0.125f * 1.4426950408889634f : 1.0f;
    unsigned short* base = qkv + ((size_t)ph * SEQ + s) * HD + chunk * 8;
    short8 v = *reinterpret_cast<short8*>(base);
    short8 o;
    const float k = -13.287712379549449f / 32.0f;
#pragma unroll
    for (int j = 0; j < 4; ++j) {
        int i = chunk * 4 + j;
        float ang = p * exp2f((float)i * k);
        float sn, cs;
        sincosf(ang, &sn, &cs);
        float x1 = bf2f((unsigned short)v[2 * j]);
        float x2 = bf2f((unsigned short)v[2 * j + 1]);
        o[2 * j]     = (short)f2bf((x1 * cs - x2 * sn) * scale);
        o[2 * j + 1] = (short)f2bf((x1 * sn + x2 * cs) * scale);
    }
    *reinterpret_cast<short8*>(base) = o;
}

// ---------------- V transpose: [s][d] -> VT [h][d][s] ----------------
__global__ __launch_bounds__(256) void transpose_v(const unsigned short* __restrict__ qkv,
                                                   unsigned short* __restrict__ vt) {
    const int st = blockIdx.x;
    const int h = blockIdx.y;
    __shared__ unsigned short tile[64][72];
    const unsigned short* Vg = qkv + (size_t)((2 * HEADS + h) * SEQ) * HD;
    const int tid = threadIdx.x;
#pragma unroll
    for (int j = 0; j < 2; ++j) {
        int b = (tid + j * 256) * 8;
        int row = b >> 6;
        int col = b & 63;
        short8 v = *reinterpret_cast<const short8*>(Vg + (size_t)(st * 64 + row) * HD + col);
#pragma unroll
        for (int i = 0; i < 8; ++i) tile[row][col + i] = (unsigned short)v[i];
    }
    __syncthreads();
#pragma unroll
    for (int j = 0; j < 2; ++j) {
        int b = (tid + j * 256) * 8;
        int d = b >> 6;
        int sc = b & 63;
        short8 o;
#pragma unroll
        for (int i = 0; i < 8; ++i) o[i] = (short)tile[sc + i][d];
        *reinterpret_cast<short8*>(vt + (size_t)(h * HD + d) * SEQ + st * 64 + sc) = o;
    }
}

// ---------------- causal flash attention ----------------
// Persistent 2-wave workers, 32x32x16 MFMA (32 q-rows/wave), in-register softmax+P,
// per-XCD LPT task queue, 3-buffer counted-vmcnt pipeline.
__global__ __launch_bounds__(128) void attn_kernel(const unsigned short* __restrict__ qkv,
                                                   const unsigned short* __restrict__ vt,
                                                   unsigned short* __restrict__ attnout,
                                                   int* __restrict__ qcnt) {
    const int xcd = blockIdx.x & 7;
    const int tid = threadIdx.x;
    const int wave = tid >> 6, lane = tid & 63;
    const int l32 = lane & 31, hi = lane >> 5;

    alignas(16) __shared__ unsigned short k_lds[3][64 * 64];
    alignas(16) __shared__ unsigned short v_lds[3][64 * 64];
    __shared__ int task_slot;

    const int rsw = (l32 & 7) << 4;  // read swizzle (row & 7) — same for row and row+32

    for (;;) {
        if (tid == 0) task_slot = atomicAdd(&qcnt[xcd], 1);
        __syncthreads();
        const int t = task_slot;
        __syncthreads();
        if (t >= 128) break;
        const int h = xcd * 2 + (t & 1);
        const int qb = 63 - (t >> 1);   // LPT: longest tasks first

        const unsigned short* Qg = qkv + (size_t)((0 * HEADS + h) * SEQ) * HD;
        const unsigned short* Kg = qkv + (size_t)((1 * HEADS + h) * SEQ) * HD;
        const unsigned short* VTg = vt + (size_t)h * HD * SEQ;

        const int qbase = qb * 64 + wave * 32;
        const int qrow = qbase + l32;

        // Q B-frags (32x32x16): lane holds q=l32, d = 16*t + hi*8 .. +7
        bf16x8 qf[4];
#pragma unroll
        for (int tt = 0; tt < 4; ++tt)
            qf[tt] = *reinterpret_cast<const bf16x8*>(Qg + (size_t)qrow * HD + tt * 16 + hi * 8);

        f32x16 oa = {}, ob = {};
        float m_r = -1e30f, l_r = 0.f;

        // wave stages its 32 rows of K and of VT: 8 gload16/wave/tile
        auto STAGE = [&](int b, int kt) {
#pragma unroll
            for (int i = 0; i < 4; ++i) {
                int base = wave * 4096 + i * 1024;
                int byte = base + lane * 16;
                int row = byte >> 7;
                int c8s = ((byte >> 4) & 7) ^ (row & 7);
                gload16(Kg + (size_t)(kt * 64 + row) * HD + c8s * 8, (char*)k_lds[b] + base);
                gload16(VTg + (size_t)row * SEQ + kt * 64 + c8s * 8, (char*)v_lds[b] + base);
            }
        };

        STAGE(0, 0);
        if (qb >= 1) STAGE(1, 1);

        for (int kt = 0; kt <= qb; ++kt) {
            const int cur = kt % 3;
            if (kt < qb) asm volatile("s_waitcnt vmcnt(8)" ::: "memory");
            else         asm volatile("s_waitcnt vmcnt(0)" ::: "memory");
            __builtin_amdgcn_s_barrier();
            if (kt + 2 <= qb) STAGE((kt + 2) % 3, kt + 2);

            const bool doT1 = (kt * 64 + 32) <= (qbase + 31);

            // S^T = K * Q : lane holds S[q=l32][kv=(r&3)+8*(r>>2)+4*hi (+32 for s1)]
            f32x16 s0 = {}, s1 = {};
            __builtin_amdgcn_s_setprio(1);
#pragma unroll
            for (int tt = 0; tt < 4; ++tt) {
                bf16x8 kf = *reinterpret_cast<const bf16x8*>(
                    (char*)k_lds[cur] + l32 * 128 + ((tt * 32 + hi * 16) ^ rsw));
                s0 = __builtin_amdgcn_mfma_f32_32x32x16_bf16(kf, qf[tt], s0, 0, 0, 0);
            }
            if (doT1) {
#pragma unroll
                for (int tt = 0; tt < 4; ++tt) {
                    bf16x8 kf = *reinterpret_cast<const bf16x8*>(
                        (char*)k_lds[cur] + (32 + l32) * 128 + ((tt * 32 + hi * 16) ^ rsw));
                    s1 = __builtin_amdgcn_mfma_f32_32x32x16_bf16(kf, qf[tt], s1, 0, 0, 0);
                }
            }
            __builtin_amdgcn_s_setprio(0);

            // causal mask (also forces skipped T1 to -inf)
            if (kt * 64 + 63 > qbase) {
#pragma unroll
                for (int r = 0; r < 16; ++r) {
                    int kv0 = kt * 64 + (r & 3) + 8 * (r >> 2) + 4 * hi;
                    if (kv0 > qrow) s0[r] = -1e30f;
                    if (kv0 + 32 > qrow) s1[r] = -1e30f;
                }
            }

            // row max over full 64: 32 in-lane + 1 shuffle
            float ma = -1e30f, mb = -1e30f, mc = -1e30f, md = -1e30f;
#pragma unroll
            for (int r = 0; r < 16; r += 4) {
                ma = fmaxf(ma, fmaxf(s0[r], s1[r]));
                mb = fmaxf(mb, fmaxf(s0[r + 1], s1[r + 1]));
                mc = fmaxf(mc, fmaxf(s0[r + 2], s1[r + 2]));
                md = fmaxf(md, fmaxf(s0[r + 3], s1[r + 3]));
            }
            float mx = fmaxf(fmaxf(ma, mb), fmaxf(mc, md));
            mx = fmaxf(mx, __shfl_xor(mx, 32));

            // defer-max (log2 domain, THR=8)
            if (__any(mx > m_r + 8.0f)) {
                float mnew = fmaxf(m_r, mx);
                float alpha = __builtin_amdgcn_exp2f(m_r - mnew);
                m_r = mnew;
#pragma unroll
                for (int r = 0; r < 16; ++r) { oa[r] *= alpha; ob[r] *= alpha; }
                l_r *= alpha;
            }

#pragma unroll
            for (int r = 0; r < 16; ++r) {
                s0[r] = __builtin_amdgcn_exp2f(s0[r] - m_r);
                s1[r] = __builtin_amdgcn_exp2f(s1[r] - m_r);
            }

            // row sum: 32 in-lane + 1 shuffle
            float ra = 0.f, rb = 0.f;
#pragma unroll
            for (int r = 0; r < 16; r += 2) {
                ra += s0[r] + s1[r];
                rb += s0[r + 1] + s1[r + 1];
            }
            float rs = ra + rb;
            rs += __shfl_xor(rs, 32);
            l_r += rs;

            // in-register P re-fragmentation: B-frags for PV (kv-chunk 16*t)
            u32x4 pfw[4];
#pragma unroll
            for (int u = 0; u < 2; ++u) {
                {   // tile 0 -> steps t = u
                    unsigned wA = cvt_pk_bf16(s0[8 * u + 0], s0[8 * u + 1]);
                    unsigned wC = cvt_pk_bf16(s0[8 * u + 2], s0[8 * u + 3]);
                    unsigned wB = cvt_pk_bf16(s0[8 * u + 4], s0[8 * u + 5]);
                    unsigned wD = cvt_pk_bf16(s0[8 * u + 6], s0[8 * u + 7]);
                    unsigned wAx = __shfl_xor((int)wA, 32), wBx = __shfl_xor((int)wB, 32);
                    unsigned wCx = __shfl_xor((int)wC, 32), wDx = __shfl_xor((int)wD, 32);
                    pfw[u][0] = hi ? wBx : wA;
                    pfw[u][1] = hi ? wDx : wC;
                    pfw[u][2] = hi ? wB : wAx;
                    pfw[u][3] = hi ? wD : wCx;
                }
                if (doT1) {  // tile 1 -> steps t = 2+u
                    unsigned wA = cvt_pk_bf16(s1[8 * u + 0], s1[8 * u + 1]);
                    unsigned wC = cvt_pk_bf16(s1[8 * u + 2], s1[8 * u + 3]);
                    unsigned wB = cvt_pk_bf16(s1[8 * u + 4], s1[8 * u + 5]);
                    unsigned wD = cvt_pk_bf16(s1[8 * u + 6], s1[8 * u + 7]);
                    unsigned wAx = __shfl_xor((int)wA, 32), wBx = __shfl_xor((int)wB, 32);
                    unsigned wCx = __shfl_xor((int)wC, 32), wDx = __shfl_xor((int)wD, 32);
                    pfw[2 + u][0] = hi ? wBx : wA;
                    pfw[2 + u][1] = hi ? wDx : wC;
                    pfw[2 + u][2] = hi ? wB : wAx;
                    pfw[2 + u][3] = hi ? wD : wCx;
                }
            }

            // O^T += VT * P^T
            __builtin_amdgcn_s_setprio(1);
#pragma unroll
            for (int tt = 0; tt < 2; ++tt) {
                bf16x8 pf = __builtin_bit_cast(bf16x8, pfw[tt]);
                bf16x8 va = *reinterpret_cast<const bf16x8*>(
                    (char*)v_lds[cur] + l32 * 128 + ((tt * 32 + hi * 16) ^ rsw));
                oa = __builtin_amdgcn_mfma_f32_32x32x16_bf16(va, pf, oa, 0, 0, 0);
                bf16x8 vb = *reinterpret_cast<const bf16x8*>(
                    (char*)v_lds[cur] + (32 + l32) * 128 + ((tt * 32 + hi * 16) ^ rsw));
                ob = __builtin_amdgcn_mfma_f32_32x32x16_bf16(vb, pf, ob, 0, 0, 0);
            }
            if (doT1) {
#pragma unroll
                for (int tt = 2; tt < 4; ++tt) {
                    bf16x8 pf = __builtin_bit_cast(bf16x8, pfw[tt]);
                    bf16x8 va = *reinterpret_cast<const bf16x8*>(
                        (char*)v_lds[cur] + l32 * 128 + ((tt * 32 + hi * 16) ^ rsw));
                    oa = __builtin_amdgcn_mfma_f32_32x32x16_bf16(va, pf, oa, 0, 0, 0);
                    bf16x8 vb = *reinterpret_cast<const bf16x8*>(
                        (char*)v_lds[cur] + (32 + l32) * 128 + ((tt * 32 + hi * 16) ^ rsw));
                    ob = __builtin_amdgcn_mfma_f32_32x32x16_bf16(vb, pf, ob, 0, 0, 0);
                }
            }
            __builtin_amdgcn_s_setprio(0);
        }

        // epilogue: lane holds O[q=qrow][d=(r&3)+8*(r>>2)+4*hi (+32 for ob)]
        float inv = 1.0f / l_r;
        unsigned short* orow = attnout + (size_t)qrow * DMODEL + h * HD;
#pragma unroll
        for (int rq = 0; rq < 4; ++rq) {
            ushort4 pa, pb;
            pa.x = f2bf(oa[4 * rq + 0] * inv); pa.y = f2bf(oa[4 * rq + 1] * inv);
            pa.z = f2bf(oa[4 * rq + 2] * inv); pa.w = f2bf(oa[4 * rq + 3] * inv);
            pb.x = f2bf(ob[4 * rq + 0] * inv); pb.y = f2bf(ob[4 * rq + 1] * inv);
            pb.z = f2bf(ob[4 * rq + 2] * inv); pb.w = f2bf(ob[4 * rq + 3] * inv);
            int dbase = 8 * rq + 4 * hi;
            *reinterpret_cast<ushort4*>(orow + dbase) = pa;
            *reinterpret_cast<ushort4*>(orow + 32 + dbase) = pb;
        }
    }
}

extern "C" void kernel_launch(void* const* d_in, const int* in_sizes, int n_in,
                              void* d_out, int out_size, void* d_ws, size_t ws_size,
                              hipStream_t stream) {
    const float* x = (const float*)d_in[0];
    const int* pos = (const int*)d_in[1];
    const float* wqkv = (const float*)d_in[2];
    const float* wo = (const float*)d_in[3];
    float* out = (float*)d_out;

    unsigned short* xb = (unsigned short*)d_ws;
    unsigned short* wqkvb = xb + (size_t)SEQ * DMODEL;
    unsigned short* wob = wqkvb + (size_t)NQKV * DMODEL;
    unsigned short* qkvp = wob + (size_t)DMODEL * DMODEL;
    unsigned short* vt = qkvp + (size_t)3 * HEADS * SEQ * HD;
    unsigned short* attnb = vt + (size_t)HEADS * HD * SEQ;
    int* qcnt = (int*)xb;  // xb is dead after gemm1; reused for queue counters

    f2bf_vec<<<2048, 256, 0, stream>>>(x, xb, SEQ * DMODEL / 4);
    f2bf_vec<<<2048, 256, 0, stream>>>(wqkv, wqkvb, NQKV * DMODEL / 4);
    f2bf_vec<<<1024, 256, 0, stream>>>(wo, wob, DMODEL * DMODEL / 4);

    dim3 g1(SEQ / 128, NQKV / 128);
    gemm_bt<0><<<g1, 256, 0, stream>>>(xb, wqkvb, nullptr, qkvp, SEQ, NQKV, DMODEL);

    rope_kernel<<<(2 * HEADS * SEQ * 8) / 256, 256, 0, stream>>>(qkvp, pos);
    transpose_v<<<dim3(SEQ / 64, HEADS), 256, 0, stream>>>(qkvp, vt);

    hipMemsetAsync(qcnt, 0, 8 * sizeof(int), stream);
    attn_kernel<<<768, 128, 0, stream>>>(qkvp, vt, attnb, qcnt);

    dim3 g2(SEQ / 128, DMODEL / 128);
    gemm_bt<1><<<g2, 256, 0, stream>>>(attnb, wob, out, nullptr, SEQ, DMODEL, DMODEL);
}

// Round 9
// 163.791 us; speedup vs baseline: 1.3058x; 1.3058x over previous
//
#include <hip/hip_runtime.h>

#define SEQ 4096
#define DMODEL 1024
#define HEADS 16
#define HD 64
#define NQKV 3072

typedef __attribute__((ext_vector_type(8))) __bf16 bf16x8;
typedef __attribute__((ext_vector_type(4))) __bf16 bf16x4;
typedef __attribute__((ext_vector_type(8))) short short8;
typedef __attribute__((ext_vector_type(4))) float f32x4;

__device__ __forceinline__ unsigned short f2bf(float f) {
    unsigned u = __builtin_bit_cast(unsigned, f);
    return (unsigned short)((u + 0x7fffu + ((u >> 16) & 1u)) >> 16);
}
__device__ __forceinline__ float bf2f(unsigned short h) {
    return __builtin_bit_cast(float, (unsigned)h << 16);
}

__device__ __forceinline__ void gload16(const void* g, void* l) {
    __builtin_amdgcn_global_load_lds(
        (const __attribute__((address_space(1))) unsigned int*)g,
        (__attribute__((address_space(3))) unsigned int*)l, 16, 0, 0);
}

// ---------------- fp32 -> bf16 convert, all three tensors in one launch ----------------
// Destinations xb|wqkvb|wob are contiguous; sources differ.
__global__ void f2bf_all(const float* __restrict__ x, const float* __restrict__ wqkv,
                         const float* __restrict__ wo, unsigned short* __restrict__ dst) {
    const int N0 = SEQ * DMODEL / 4;            // 1048576
    const int N1 = N0 + NQKV * DMODEL / 4;      // 1835008
    const int NT = N1 + DMODEL * DMODEL / 4;    // 2097152
    int i = blockIdx.x * 256 + threadIdx.x;
    int stride = gridDim.x * 256;
    for (; i < NT; i += stride) {
        const float4* src;
        if (i < N0)      src = reinterpret_cast<const float4*>(x) + i;
        else if (i < N1) src = reinterpret_cast<const float4*>(wqkv) + (i - N0);
        else             src = reinterpret_cast<const float4*>(wo) + (i - N1);
        float4 f = *src;
        ushort4 o;
        o.x = f2bf(f.x); o.y = f2bf(f.y); o.z = f2bf(f.z); o.w = f2bf(f.w);
        reinterpret_cast<ushort4*>(dst)[i] = o;
    }
}

// ---------------- bf16 GEMM, C = A(MxK) * B(NxK)^T ----------------
template <int EPI>
__global__ __launch_bounds__(256) void gemm_bt(const unsigned short* __restrict__ A,
                                               const unsigned short* __restrict__ B,
                                               float* __restrict__ outF,
                                               unsigned short* __restrict__ outB,
                                               int M, int N, int K) {
    alignas(16) __shared__ unsigned short a_lds[128 * 32];
    alignas(16) __shared__ unsigned short b_lds[128 * 32];
    const int tid = threadIdx.x;
    const int wave = tid >> 6, lane = tid & 63;
    const int l16 = lane & 15, g = lane >> 4;
    const int wr = wave >> 1, wc = wave & 1;
    const int bm = blockIdx.x, bn = blockIdx.y;

    const int lrow = lane >> 2;
    const int lcol = (lane & 3) * 8;

    const unsigned short* Ag = A + (size_t)(bm * 128 + lrow) * K + lcol;
    const unsigned short* Bg = B + (size_t)(bn * 128 + lrow) * K + lcol;

    f32x4 acc[4][4] = {};

    for (int k0 = 0; k0 < K; k0 += 32) {
#pragma unroll
        for (int j = 0; j < 2; ++j) {
            int chunk = wave * 2 + j;
            gload16(Ag + (size_t)(chunk * 16) * K + k0, a_lds + chunk * 512);
            gload16(Bg + (size_t)(chunk * 16) * K + k0, b_lds + chunk * 512);
        }
        __syncthreads();
        bf16x8 af[4], bfr[4];
#pragma unroll
        for (int m = 0; m < 4; ++m)
            af[m] = *reinterpret_cast<const bf16x8*>(a_lds + (wr * 64 + m * 16 + l16) * 32 + g * 8);
#pragma unroll
        for (int n = 0; n < 4; ++n)
            bfr[n] = *reinterpret_cast<const bf16x8*>(b_lds + (wc * 64 + n * 16 + l16) * 32 + g * 8);
#pragma unroll
        for (int m = 0; m < 4; ++m)
#pragma unroll
            for (int n = 0; n < 4; ++n)
                acc[m][n] = __builtin_amdgcn_mfma_f32_16x16x32_bf16(af[m], bfr[n], acc[m][n], 0, 0, 0);
        __syncthreads();
    }

#pragma unroll
    for (int m = 0; m < 4; ++m)
#pragma unroll
        for (int n = 0; n < 4; ++n)
#pragma unroll
            for (int r = 0; r < 4; ++r) {
                int row = bm * 128 + wr * 64 + m * 16 + g * 4 + r;
                int col = bn * 128 + wc * 64 + n * 16 + l16;
                float v = acc[m][n][r];
                if (EPI == 0) {
                    int part = col >> 10;
                    int hd = col & 1023;
                    int h = hd >> 6, d = hd & 63;
                    outB[(size_t)((part * HEADS + h) * SEQ + row) * HD + d] = f2bf(v);
                } else {
                    outF[(size_t)row * N + col] = v;
                }
            }
}

// ---------------- RoPE in place on Q,K (Q scaled by 1/8 * log2e) ----------------
__global__ __launch_bounds__(256) void rope_kernel(unsigned short* qkv, const int* __restrict__ pos) {
    int idx = blockIdx.x * 256 + threadIdx.x;
    int chunk = idx & 7;
    int row = idx >> 3;
    int s = row & (SEQ - 1);
    int ph = row >> 12;
    float p = (float)pos[s];
    float scale = (ph < HEADS) ? 0.125f * 1.4426950408889634f : 1.0f;
    unsigned short* base = qkv + ((size_t)ph * SEQ + s) * HD + chunk * 8;
    short8 v = *reinterpret_cast<short8*>(base);
    short8 o;
    const float k = -13.287712379549449f / 32.0f;
#pragma unroll
    for (int j = 0; j < 4; ++j) {
        int i = chunk * 4 + j;
        float ang = p * exp2f((float)i * k);
        float sn, cs;
        sincosf(ang, &sn, &cs);
        float x1 = bf2f((unsigned short)v[2 * j]);
        float x2 = bf2f((unsigned short)v[2 * j + 1]);
        o[2 * j]     = (short)f2bf((x1 * cs - x2 * sn) * scale);
        o[2 * j + 1] = (short)f2bf((x1 * sn + x2 * cs) * scale);
    }
    *reinterpret_cast<short8*>(base) = o;
}

// ---------------- V transpose: [s][d] -> VT [h][d][s] ----------------
__global__ __launch_bounds__(256) void transpose_v(const unsigned short* __restrict__ qkv,
                                                   unsigned short* __restrict__ vt) {
    const int st = blockIdx.x;
    const int h = blockIdx.y;
    __shared__ unsigned short tile[64][72];
    const unsigned short* Vg = qkv + (size_t)((2 * HEADS + h) * SEQ) * HD;
    const int tid = threadIdx.x;
#pragma unroll
    for (int j = 0; j < 2; ++j) {
        int b = (tid + j * 256) * 8;
        int row = b >> 6;
        int col = b & 63;
        short8 v = *reinterpret_cast<const short8*>(Vg + (size_t)(st * 64 + row) * HD + col);
#pragma unroll
        for (int i = 0; i < 8; ++i) tile[row][col + i] = (unsigned short)v[i];
    }
    __syncthreads();
#pragma unroll
    for (int j = 0; j < 2; ++j) {
        int b = (tid + j * 256) * 8;
        int d = b >> 6;
        int sc = b & 63;
        short8 o;
#pragma unroll
        for (int i = 0; i < 8; ++i) o[i] = (short)tile[sc + i][d];
        *reinterpret_cast<short8*>(vt + (size_t)(h * HD + d) * SEQ + st * 64 + sc) = o;
    }
}

// ---------------- causal flash attention (R5 kernel, known-good) ----------------
// QBLK=128, 8 waves; 3-buffer 2-deep counted-vmcnt pipeline; head->XCD affinity;
// balanced qb pairing so every CU gets a (qb, 31-qb) pair = constant 68 tiles.
__global__ __launch_bounds__(512) void attn_kernel(const unsigned short* __restrict__ qkv,
                                                   const unsigned short* __restrict__ vt,
                                                   unsigned short* __restrict__ attnout) {
    const int bid = blockIdx.x;
    const int xcd = bid & 7;
    const int slt = bid >> 3;                 // 0..63
    const int j = slt & 31, half = slt >> 5;
    const int h = xcd * 2 + (j & 1);
    const int qb = half ? (j >> 1) : (31 - (j >> 1));  // pairs sum to 31 per CU
    const int last = 2 * qb + 1;              // K-tiles 0..last (64-wide)

    const int tid = threadIdx.x;
    const int wave = tid >> 6, lane = tid & 63;
    const int l16 = lane & 15, g = lane >> 4;

    alignas(16) __shared__ unsigned short k_lds[3][64 * 64];
    alignas(16) __shared__ unsigned short v_lds[3][64 * 64];
    alignas(16) __shared__ unsigned short p_lds[8][16 * 64];

    const unsigned short* Qg = qkv + (size_t)((0 * HEADS + h) * SEQ) * HD;
    const unsigned short* Kg = qkv + (size_t)((1 * HEADS + h) * SEQ) * HD;
    const unsigned short* VTg = vt + (size_t)h * HD * SEQ;

    const int qbase = qb * 128 + wave * 16;
    bf16x8 qf[2];
    qf[0] = *reinterpret_cast<const bf16x8*>(Qg + (size_t)(qbase + l16) * HD + g * 8);
    qf[1] = *reinterpret_cast<const bf16x8*>(Qg + (size_t)(qbase + l16) * HD + 32 + g * 8);

    bf16x8 ones;
#pragma unroll
    for (int j2 = 0; j2 < 8; ++j2) ones[j2] = (__bf16)1.0f;

    f32x4 o_acc[4] = {};
    f32x4 l_acc = {};
    float m_r = -1e30f;

    char* pwave = (char*)p_lds + wave * 2048;
    const int rsw = (l16 & 7) << 4;

    auto STAGE = [&](int b, int kt) {
        int base = wave * 1024;
        int byte = base + lane * 16;
        int row = byte >> 7;
        int c8s = ((byte >> 4) & 7) ^ (row & 7);
        gload16(Kg + (size_t)(kt * 64 + row) * HD + c8s * 8, (char*)k_lds[b] + base);
        gload16(VTg + (size_t)row * SEQ + kt * 64 + c8s * 8, (char*)v_lds[b] + base);
    };

    STAGE(0, 0);
    STAGE(1, 1);

    for (int kt = 0; kt <= last; ++kt) {
        const int cur = kt % 3;
        if (kt < last) asm volatile("s_waitcnt vmcnt(2)" ::: "memory");
        else           asm volatile("s_waitcnt vmcnt(0)" ::: "memory");
        __builtin_amdgcn_s_barrier();
        if (kt + 2 <= last) STAGE((kt + 2) % 3, kt + 2);

        if (kt * 64 > qbase + 15) continue;

        // S^T = K * Q (log2 domain): lane holds S[q=l16][k = nt*16 + g*4 + r]
        f32x4 s[4] = {};
        __builtin_amdgcn_s_setprio(1);
#pragma unroll
        for (int nt = 0; nt < 4; ++nt) {
            int row = nt * 16 + l16;
#pragma unroll
            for (int kk = 0; kk < 2; ++kk) {
                bf16x8 kf = *reinterpret_cast<const bf16x8*>(
                    (char*)k_lds[cur] + row * 128 + (((kk * 4 + g) << 4) ^ rsw));
                s[nt] = __builtin_amdgcn_mfma_f32_16x16x32_bf16(kf, qf[kk], s[nt], 0, 0, 0);
            }
        }
        __builtin_amdgcn_s_setprio(0);

        if (kt * 64 + 63 > qbase) {
            int qrow = qbase + l16;
#pragma unroll
            for (int nt = 0; nt < 4; ++nt)
#pragma unroll
                for (int r = 0; r < 4; ++r)
                    if (kt * 64 + nt * 16 + g * 4 + r > qrow) s[nt][r] = -1e30f;
        }

        // row max: tree + 2 shuffles
        float t0 = fmaxf(fmaxf(s[0][0], s[0][1]), s[0][2]);
        float t1 = fmaxf(fmaxf(s[0][3], s[1][0]), s[1][1]);
        float t2 = fmaxf(fmaxf(s[1][2], s[1][3]), s[2][0]);
        float t3 = fmaxf(fmaxf(s[2][1], s[2][2]), s[2][3]);
        float t4 = fmaxf(fmaxf(s[3][0], s[3][1]), s[3][2]);
        float mx = fmaxf(fmaxf(fmaxf(t0, t1), t2), fmaxf(fmaxf(t3, t4), s[3][3]));
        mx = fmaxf(mx, __shfl_xor(mx, 16));
        mx = fmaxf(mx, __shfl_xor(mx, 32));

        // defer-max (log2 domain, THR=8)
        if (__any(mx > m_r + 8.0f)) {
            float mnew = fmaxf(m_r, mx);
            float alpha = __builtin_amdgcn_exp2f(m_r - mnew);
            m_r = mnew;
#pragma unroll
            for (int dt = 0; dt < 4; ++dt)
#pragma unroll
                for (int r = 0; r < 4; ++r) o_acc[dt][r] *= alpha;
            l_acc[0] *= alpha;
        }

#pragma unroll
        for (int nt = 0; nt < 4; ++nt)
#pragma unroll
            for (int r = 0; r < 4; ++r) s[nt][r] = __builtin_amdgcn_exp2f(s[nt][r] - m_r);

        // P^T pack -> per-wave LDS (swizzled), then re-fragment
#pragma unroll
        for (int nt = 0; nt < 4; ++nt) {
            bf16x4 pb;
#pragma unroll
            for (int r = 0; r < 4; ++r) pb[r] = (__bf16)s[nt][r];
            *reinterpret_cast<bf16x4*>(pwave + l16 * 128 + ((nt * 32 + g * 8) ^ rsw)) = pb;
        }
        bf16x8 pfrag[2];
#pragma unroll
        for (int kk = 0; kk < 2; ++kk)
            pfrag[kk] = *reinterpret_cast<const bf16x8*>(
                pwave + l16 * 128 + (((kk * 4 + g) << 4) ^ rsw));

        // O^T += VT * P^T ; l += ones * P^T
        __builtin_amdgcn_s_setprio(1);
#pragma unroll
        for (int dt = 0; dt < 4; ++dt) {
            int row = dt * 16 + l16;
#pragma unroll
            for (int kk = 0; kk < 2; ++kk) {
                bf16x8 vf = *reinterpret_cast<const bf16x8*>(
                    (char*)v_lds[cur] + row * 128 + (((kk * 4 + g) << 4) ^ rsw));
                o_acc[dt] = __builtin_amdgcn_mfma_f32_16x16x32_bf16(vf, pfrag[kk], o_acc[dt], 0, 0, 0);
            }
        }
        l_acc = __builtin_amdgcn_mfma_f32_16x16x32_bf16(ones, pfrag[0], l_acc, 0, 0, 0);
        l_acc = __builtin_amdgcn_mfma_f32_16x16x32_bf16(ones, pfrag[1], l_acc, 0, 0, 0);
        __builtin_amdgcn_s_setprio(0);
    }

    // epilogue
    float inv = 1.0f / l_acc[0];
    int q = qbase + l16;
#pragma unroll
    for (int dt = 0; dt < 4; ++dt) {
        ushort4 ov;
        ov.x = f2bf(o_acc[dt][0] * inv);
        ov.y = f2bf(o_acc[dt][1] * inv);
        ov.z = f2bf(o_acc[dt][2] * inv);
        ov.w = f2bf(o_acc[dt][3] * inv);
        *reinterpret_cast<ushort4*>(attnout + (size_t)q * DMODEL + h * HD + dt * 16 + g * 4) = ov;
    }
}

extern "C" void kernel_launch(void* const* d_in, const int* in_sizes, int n_in,
                              void* d_out, int out_size, void* d_ws, size_t ws_size,
                              hipStream_t stream) {
    const float* x = (const float*)d_in[0];
    const int* pos = (const int*)d_in[1];
    const float* wqkv = (const float*)d_in[2];
    const float* wo = (const float*)d_in[3];
    float* out = (float*)d_out;

    unsigned short* xb = (unsigned short*)d_ws;
    unsigned short* wqkvb = xb + (size_t)SEQ * DMODEL;
    unsigned short* wob = wqkvb + (size_t)NQKV * DMODEL;
    unsigned short* qkvp = wob + (size_t)DMODEL * DMODEL;
    unsigned short* vt = qkvp + (size_t)3 * HEADS * SEQ * HD;
    unsigned short* attnb = vt + (size_t)HEADS * HD * SEQ;

    f2bf_all<<<2048, 256, 0, stream>>>(x, wqkv, wo, xb);

    dim3 g1(SEQ / 128, NQKV / 128);
    gemm_bt<0><<<g1, 256, 0, stream>>>(xb, wqkvb, nullptr, qkvp, SEQ, NQKV, DMODEL);

    rope_kernel<<<(2 * HEADS * SEQ * 8) / 256, 256, 0, stream>>>(qkvp, pos);
    transpose_v<<<dim3(SEQ / 64, HEADS), 256, 0, stream>>>(qkvp, vt);
    attn_kernel<<<512, 512, 0, stream>>>(qkvp, vt, attnb);

    dim3 g2(SEQ / 128, DMODEL / 128);
    gemm_bt<1><<<g2, 256, 0, stream>>>(attnb, wob, out, nullptr, SEQ, DMODEL, DMODEL);
}

// Round 10
// 148.930 us; speedup vs baseline: 1.4361x; 1.0998x over previous
//
#include <hip/hip_runtime.h>

#define SEQ 4096
#define DMODEL 1024
#define HEADS 16
#define HD 64
#define NQKV 3072

typedef __attribute__((ext_vector_type(8))) __bf16 bf16x8;
typedef __attribute__((ext_vector_type(4))) __bf16 bf16x4;
typedef __attribute__((ext_vector_type(8))) short short8;
typedef __attribute__((ext_vector_type(4))) float f32x4;

__device__ __forceinline__ unsigned short f2bf(float f) {
    unsigned u = __builtin_bit_cast(unsigned, f);
    return (unsigned short)((u + 0x7fffu + ((u >> 16) & 1u)) >> 16);
}
__device__ __forceinline__ float bf2f(unsigned short h) {
    return __builtin_bit_cast(float, (unsigned)h << 16);
}

__device__ __forceinline__ void gload16(const void* g, void* l) {
    __builtin_amdgcn_global_load_lds(
        (const __attribute__((address_space(1))) unsigned int*)g,
        (__attribute__((address_space(3))) unsigned int*)l, 16, 0, 0);
}

// ---------------- fp32 -> bf16 convert, all three tensors in one launch ----------------
__global__ void f2bf_all(const float* __restrict__ x, const float* __restrict__ wqkv,
                         const float* __restrict__ wo, unsigned short* __restrict__ dst) {
    const int N0 = SEQ * DMODEL / 4;
    const int N1 = N0 + NQKV * DMODEL / 4;
    const int NT = N1 + DMODEL * DMODEL / 4;
    int i = blockIdx.x * 256 + threadIdx.x;
    int stride = gridDim.x * 256;
    for (; i < NT; i += stride) {
        const float4* src;
        if (i < N0)      src = reinterpret_cast<const float4*>(x) + i;
        else if (i < N1) src = reinterpret_cast<const float4*>(wqkv) + (i - N0);
        else             src = reinterpret_cast<const float4*>(wo) + (i - N1);
        float4 f = *src;
        ushort4 o;
        o.x = f2bf(f.x); o.y = f2bf(f.y); o.z = f2bf(f.z); o.w = f2bf(f.w);
        reinterpret_cast<ushort4*>(dst)[i] = o;
    }
}

// ---------------- bf16 GEMM, C = A(MxK) * B(NxK)^T ----------------
// 2-buffer prefetch pipeline: 1 barrier per k-step, loads fly under compute.
template <int EPI>
__global__ __launch_bounds__(256) void gemm_bt(const unsigned short* __restrict__ A,
                                               const unsigned short* __restrict__ B,
                                               float* __restrict__ outF,
                                               unsigned short* __restrict__ outB,
                                               int M, int N, int K) {
    alignas(16) __shared__ unsigned short a_lds[2][128 * 32];
    alignas(16) __shared__ unsigned short b_lds[2][128 * 32];
    const int tid = threadIdx.x;
    const int wave = tid >> 6, lane = tid & 63;
    const int l16 = lane & 15, g = lane >> 4;
    const int wr = wave >> 1, wc = wave & 1;
    const int bm = blockIdx.x, bn = blockIdx.y;

    const int lrow = lane >> 2;
    const int lcol = (lane & 3) * 8;

    const unsigned short* Ag = A + (size_t)(bm * 128 + lrow) * K + lcol;
    const unsigned short* Bg = B + (size_t)(bn * 128 + lrow) * K + lcol;

    f32x4 acc[4][4] = {};
    const int NS = K / 32;

    auto STAGE = [&](int b, int ks) {
#pragma unroll
        for (int j = 0; j < 2; ++j) {
            int chunk = wave * 2 + j;
            gload16(Ag + (size_t)(chunk * 16) * K + ks * 32, a_lds[b] + chunk * 512);
            gload16(Bg + (size_t)(chunk * 16) * K + ks * 32, b_lds[b] + chunk * 512);
        }
    };

    STAGE(0, 0);

    for (int ks = 0; ks < NS; ++ks) {
        const int cur = ks & 1;
        asm volatile("s_waitcnt vmcnt(0)" ::: "memory");
        __builtin_amdgcn_s_barrier();
        if (ks + 1 < NS) STAGE(cur ^ 1, ks + 1);

        bf16x8 af[4], bfr[4];
#pragma unroll
        for (int m = 0; m < 4; ++m)
            af[m] = *reinterpret_cast<const bf16x8*>(a_lds[cur] + (wr * 64 + m * 16 + l16) * 32 + g * 8);
#pragma unroll
        for (int n = 0; n < 4; ++n)
            bfr[n] = *reinterpret_cast<const bf16x8*>(b_lds[cur] + (wc * 64 + n * 16 + l16) * 32 + g * 8);
        __builtin_amdgcn_s_setprio(1);
#pragma unroll
        for (int m = 0; m < 4; ++m)
#pragma unroll
            for (int n = 0; n < 4; ++n)
                acc[m][n] = __builtin_amdgcn_mfma_f32_16x16x32_bf16(af[m], bfr[n], acc[m][n], 0, 0, 0);
        __builtin_amdgcn_s_setprio(0);
    }

#pragma unroll
    for (int m = 0; m < 4; ++m)
#pragma unroll
        for (int n = 0; n < 4; ++n)
#pragma unroll
            for (int r = 0; r < 4; ++r) {
                int row = bm * 128 + wr * 64 + m * 16 + g * 4 + r;
                int col = bn * 128 + wc * 64 + n * 16 + l16;
                float v = acc[m][n][r];
                if (EPI == 0) {
                    int part = col >> 10;
                    int hd = col & 1023;
                    int h = hd >> 6, d = hd & 63;
                    outB[(size_t)((part * HEADS + h) * SEQ + row) * HD + d] = f2bf(v);
                } else {
                    outF[(size_t)row * N + col] = v;
                }
            }
}

// ---------------- RoPE in place on Q,K (Q scaled by 1/8 * log2e) ----------------
__global__ __launch_bounds__(256) void rope_kernel(unsigned short* qkv, const int* __restrict__ pos) {
    int idx = blockIdx.x * 256 + threadIdx.x;
    int chunk = idx & 7;
    int row = idx >> 3;
    int s = row & (SEQ - 1);
    int ph = row >> 12;
    float p = (float)pos[s];
    float scale = (ph < HEADS) ? 0.125f * 1.4426950408889634f : 1.0f;
    unsigned short* base = qkv + ((size_t)ph * SEQ + s) * HD + chunk * 8;
    short8 v = *reinterpret_cast<short8*>(base);
    short8 o;
    const float k = -13.287712379549449f / 32.0f;
#pragma unroll
    for (int j = 0; j < 4; ++j) {
        int i = chunk * 4 + j;
        float ang = p * exp2f((float)i * k);
        float sn, cs;
        sincosf(ang, &sn, &cs);
        float x1 = bf2f((unsigned short)v[2 * j]);
        float x2 = bf2f((unsigned short)v[2 * j + 1]);
        o[2 * j]     = (short)f2bf((x1 * cs - x2 * sn) * scale);
        o[2 * j + 1] = (short)f2bf((x1 * sn + x2 * cs) * scale);
    }
    *reinterpret_cast<short8*>(base) = o;
}

// ---------------- V transpose: [s][d] -> VT [h][d][s] ----------------
__global__ __launch_bounds__(256) void transpose_v(const unsigned short* __restrict__ qkv,
                                                   unsigned short* __restrict__ vt) {
    const int st = blockIdx.x;
    const int h = blockIdx.y;
    __shared__ unsigned short tile[64][72];
    const unsigned short* Vg = qkv + (size_t)((2 * HEADS + h) * SEQ) * HD;
    const int tid = threadIdx.x;
#pragma unroll
    for (int j = 0; j < 2; ++j) {
        int b = (tid + j * 256) * 8;
        int row = b >> 6;
        int col = b & 63;
        short8 v = *reinterpret_cast<const short8*>(Vg + (size_t)(st * 64 + row) * HD + col);
#pragma unroll
        for (int i = 0; i < 8; ++i) tile[row][col + i] = (unsigned short)v[i];
    }
    __syncthreads();
#pragma unroll
    for (int j = 0; j < 2; ++j) {
        int b = (tid + j * 256) * 8;
        int d = b >> 6;
        int sc = b & 63;
        short8 o;
#pragma unroll
        for (int i = 0; i < 8; ++i) o[i] = (short)tile[sc + i][d];
        *reinterpret_cast<short8*>(vt + (size_t)(h * HD + d) * SEQ + st * 64 + sc) = o;
    }
}

// ---------------- causal flash attention ----------------
// QBLK=128, KVBLK=128, 8 waves; 2-buffer full-phase prefetch; head->XCD affinity;
// balanced qb pairing; PV in two 64-kv halves reusing per-wave P buffer. 80KB LDS.
__global__ __launch_bounds__(512) void attn_kernel(const unsigned short* __restrict__ qkv,
                                                   const unsigned short* __restrict__ vt,
                                                   unsigned short* __restrict__ attnout) {
    const int bid = blockIdx.x;
    const int xcd = bid & 7;
    const int slt = bid >> 3;                 // 0..63
    const int j = slt & 31, hlf = slt >> 5;
    const int h = xcd * 2 + (j & 1);
    const int qb = hlf ? (j >> 1) : (31 - (j >> 1));  // pairs sum to 31 per CU
    // K-tiles 0..qb (128-wide)

    const int tid = threadIdx.x;
    const int wave = tid >> 6, lane = tid & 63;
    const int l16 = lane & 15, g = lane >> 4;

    alignas(16) __shared__ unsigned short k_lds[2][128 * 64];  // [kv][d], 128B rows
    alignas(16) __shared__ unsigned short v_lds[2][64 * 128];  // [d][kv], 256B rows
    alignas(16) __shared__ unsigned short p_lds[8][16 * 64];   // per-wave [q][kv-half]

    const unsigned short* Qg = qkv + (size_t)((0 * HEADS + h) * SEQ) * HD;
    const unsigned short* Kg = qkv + (size_t)((1 * HEADS + h) * SEQ) * HD;
    const unsigned short* VTg = vt + (size_t)h * HD * SEQ;

    const int qbase = qb * 128 + wave * 16;
    bf16x8 qf[2];
    qf[0] = *reinterpret_cast<const bf16x8*>(Qg + (size_t)(qbase + l16) * HD + g * 8);
    qf[1] = *reinterpret_cast<const bf16x8*>(Qg + (size_t)(qbase + l16) * HD + 32 + g * 8);

    bf16x8 ones;
#pragma unroll
    for (int j2 = 0; j2 < 8; ++j2) ones[j2] = (__bf16)1.0f;

    f32x4 o_acc[4] = {};
    f32x4 l_acc = {};
    float m_r = -1e30f;

    char* pwave = (char*)p_lds + wave * 2048;
    const int rsw = (l16 & 7) << 4;

    // wave stages 16 K-rows (2KB) + 8 V-rows (2KB) per tile: 4 gload16
    auto STAGE = [&](int b, int kt) {
#pragma unroll
        for (int i = 0; i < 2; ++i) {
            int base = wave * 2048 + i * 1024;
            int byte = base + lane * 16;
            int krow = byte >> 7;                       // 0..127
            int kc8 = ((byte >> 4) & 7) ^ (krow & 7);
            gload16(Kg + (size_t)(kt * 128 + krow) * HD + kc8 * 8, (char*)k_lds[b] + base);
            int vrow = byte >> 8;                       // 0..63
            int vc16 = ((byte >> 4) & 15) ^ (vrow & 7);
            gload16(VTg + (size_t)vrow * SEQ + kt * 128 + vc16 * 8, (char*)v_lds[b] + base);
        }
    };

    STAGE(0, 0);

    for (int kt = 0; kt <= qb; ++kt) {
        const int cur = kt & 1;
        // own stage loads were issued a full phase ago -> near-zero drain
        asm volatile("s_waitcnt vmcnt(0)" ::: "memory");
        __builtin_amdgcn_s_barrier();
        if (kt < qb) STAGE(cur ^ 1, kt + 1);

        const bool doB = (kt * 128 + 64) <= (qbase + 15);  // half B relevant?

        // S^T = K * Q (log2 domain): s[h*4+nt][r] = S[q=l16][kv = kt*128 + h*64 + nt*16 + g*4 + r]
        f32x4 s[8] = {};
        __builtin_amdgcn_s_setprio(1);
#pragma unroll
        for (int nt = 0; nt < 4; ++nt) {
            int row = nt * 16 + l16;
#pragma unroll
            for (int kk = 0; kk < 2; ++kk) {
                bf16x8 kf = *reinterpret_cast<const bf16x8*>(
                    (char*)k_lds[cur] + row * 128 + (((kk * 4 + g) << 4) ^ rsw));
                s[nt] = __builtin_amdgcn_mfma_f32_16x16x32_bf16(kf, qf[kk], s[nt], 0, 0, 0);
            }
        }
        if (doB) {
#pragma unroll
            for (int nt = 0; nt < 4; ++nt) {
                int row = 64 + nt * 16 + l16;
#pragma unroll
                for (int kk = 0; kk < 2; ++kk) {
                    bf16x8 kf = *reinterpret_cast<const bf16x8*>(
                        (char*)k_lds[cur] + row * 128 + (((kk * 4 + g) << 4) ^ rsw));
                    s[4 + nt] = __builtin_amdgcn_mfma_f32_16x16x32_bf16(kf, qf[kk], s[4 + nt], 0, 0, 0);
                }
            }
        }
        __builtin_amdgcn_s_setprio(0);

        // causal mask on the diagonal tile (also forces skipped half-B to -inf)
        if (kt * 128 + 127 > qbase) {
            int qrow = qbase + l16;
#pragma unroll
            for (int nt = 0; nt < 4; ++nt)
#pragma unroll
                for (int r = 0; r < 4; ++r) {
                    int kv = kt * 128 + nt * 16 + g * 4 + r;
                    if (kv > qrow) s[nt][r] = -1e30f;
                    if (kv + 64 > qrow) s[4 + nt][r] = -1e30f;
                }
        }

        // row max over 32 in-lane values + 2 shuffles
        f32x4 m4;
#pragma unroll
        for (int r = 0; r < 4; ++r) {
            float a = fmaxf(fmaxf(s[0][r], s[1][r]), fmaxf(s[2][r], s[3][r]));
            float b = fmaxf(fmaxf(s[4][r], s[5][r]), fmaxf(s[6][r], s[7][r]));
            m4[r] = fmaxf(a, b);
        }
        float mx = fmaxf(fmaxf(m4[0], m4[1]), fmaxf(m4[2], m4[3]));
        mx = fmaxf(mx, __shfl_xor(mx, 16));
        mx = fmaxf(mx, __shfl_xor(mx, 32));

        // defer-max (log2 domain, THR=8)
        if (__any(mx > m_r + 8.0f)) {
            float mnew = fmaxf(m_r, mx);
            float alpha = __builtin_amdgcn_exp2f(m_r - mnew);
            m_r = mnew;
#pragma unroll
            for (int dt = 0; dt < 4; ++dt)
#pragma unroll
                for (int r = 0; r < 4; ++r) o_acc[dt][r] *= alpha;
            l_acc[0] *= alpha;
        }

#pragma unroll
        for (int i = 0; i < 8; ++i)
#pragma unroll
            for (int r = 0; r < 4; ++r) s[i][r] = __builtin_amdgcn_exp2f(s[i][r] - m_r);

        // PV per 64-kv half, reusing the per-wave P buffer
        __builtin_amdgcn_s_setprio(1);
#pragma unroll
        for (int h64 = 0; h64 < 2; ++h64) {
            if (h64 && !doB) break;
#pragma unroll
            for (int nt = 0; nt < 4; ++nt) {
                bf16x4 pb;
#pragma unroll
                for (int r = 0; r < 4; ++r) pb[r] = (__bf16)s[h64 * 4 + nt][r];
                *reinterpret_cast<bf16x4*>(pwave + l16 * 128 + ((nt * 32 + g * 8) ^ rsw)) = pb;
            }
            bf16x8 pfrag[2];
#pragma unroll
            for (int kk = 0; kk < 2; ++kk)
                pfrag[kk] = *reinterpret_cast<const bf16x8*>(
                    pwave + l16 * 128 + (((kk * 4 + g) << 4) ^ rsw));

#pragma unroll
            for (int dt = 0; dt < 4; ++dt) {
                int row = dt * 16 + l16;
#pragma unroll
                for (int kk = 0; kk < 2; ++kk) {
                    bf16x8 vf = *reinterpret_cast<const bf16x8*>(
                        (char*)v_lds[cur] + row * 256 + ((h64 * 128 + kk * 64 + g * 16) ^ rsw));
                    o_acc[dt] = __builtin_amdgcn_mfma_f32_16x16x32_bf16(vf, pfrag[kk], o_acc[dt], 0, 0, 0);
                }
            }
            l_acc = __builtin_amdgcn_mfma_f32_16x16x32_bf16(ones, pfrag[0], l_acc, 0, 0, 0);
            l_acc = __builtin_amdgcn_mfma_f32_16x16x32_bf16(ones, pfrag[1], l_acc, 0, 0, 0);
        }
        __builtin_amdgcn_s_setprio(0);
    }

    // epilogue
    float inv = 1.0f / l_acc[0];
    int q = qbase + l16;
#pragma unroll
    for (int dt = 0; dt < 4; ++dt) {
        ushort4 ov;
        ov.x = f2bf(o_acc[dt][0] * inv);
        ov.y = f2bf(o_acc[dt][1] * inv);
        ov.z = f2bf(o_acc[dt][2] * inv);
        ov.w = f2bf(o_acc[dt][3] * inv);
        *reinterpret_cast<ushort4*>(attnout + (size_t)q * DMODEL + h * HD + dt * 16 + g * 4) = ov;
    }
}

extern "C" void kernel_launch(void* const* d_in, const int* in_sizes, int n_in,
                              void* d_out, int out_size, void* d_ws, size_t ws_size,
                              hipStream_t stream) {
    const float* x = (const float*)d_in[0];
    const int* pos = (const int*)d_in[1];
    const float* wqkv = (const float*)d_in[2];
    const float* wo = (const float*)d_in[3];
    float* out = (float*)d_out;

    unsigned short* xb = (unsigned short*)d_ws;
    unsigned short* wqkvb = xb + (size_t)SEQ * DMODEL;
    unsigned short* wob = wqkvb + (size_t)NQKV * DMODEL;
    unsigned short* qkvp = wob + (size_t)DMODEL * DMODEL;
    unsigned short* vt = qkvp + (size_t)3 * HEADS * SEQ * HD;
    unsigned short* attnb = vt + (size_t)HEADS * HD * SEQ;

    f2bf_all<<<2048, 256, 0, stream>>>(x, wqkv, wo, xb);

    dim3 g1(SEQ / 128, NQKV / 128);
    gemm_bt<0><<<g1, 256, 0, stream>>>(xb, wqkvb, nullptr, qkvp, SEQ, NQKV, DMODEL);

    rope_kernel<<<(2 * HEADS * SEQ * 8) / 256, 256, 0, stream>>>(qkvp, pos);
    transpose_v<<<dim3(SEQ / 64, HEADS), 256, 0, stream>>>(qkvp, vt);
    attn_kernel<<<512, 512, 0, stream>>>(qkvp, vt, attnb);

    dim3 g2(SEQ / 128, DMODEL / 128);
    gemm_bt<1><<<g2, 256, 0, stream>>>(attnb, wob, out, nullptr, SEQ, DMODEL, DMODEL);
}